// Round 8
// baseline (18226.680 us; speedup 1.0000x reference)
//
#include <hip/hip_runtime.h>
#include <hip/hip_bf16.h>

#define S_LEN 8192
#define CLEN 16
#define WDIM 256
#define CDIM 64
#define CHID 128
#define WHID 512
#define GDIM 2048   // 4*WHID
#define NTAG 64
#define KDIM 384    // WDIM + CHID
#define NWG 32      // workgroups in sequential kernel

typedef unsigned long long u64;

__device__ __forceinline__ float sigmoidf_(float x) {
  return 1.0f / (1.0f + __expf(-x));
}
__device__ __forceinline__ float tanhf_(float x) {
  // safe tanh: 1 - 2/(e^{2x}+1); correct limits at +-inf without NaN
  return 1.0f - 2.0f / (__expf(2.0f * x) + 1.0f);
}

// ---------------------------------------------------------------------------
// K1: batched char LSTM. 16 words per block (two groups of 8), 256 threads.
// ---------------------------------------------------------------------------
__global__ __launch_bounds__(256)
void char_lstm_kernel(const int* __restrict__ chars, const int* __restrict__ lengths,
                      const float* __restrict__ emb, const float* __restrict__ Wih,
                      const float* __restrict__ Whh, const float* __restrict__ bih,
                      const float* __restrict__ bhh, float* __restrict__ cf)
{
  __shared__ float xs[16][CDIM];
  __shared__ float hsm[16][CHID];
  __shared__ int cidx[16];
  __shared__ int lens[16];
  const int tid = threadIdx.x;
  const int grp = tid >> 7;      // 0..1 (word group)
  const int j = tid & 127;       // hidden index
  const int wb = blockIdx.x * 16;

  for (int i = tid; i < 16 * CHID; i += 256) (&hsm[0][0])[i] = 0.f;
  if (tid < 16) lens[tid] = lengths[wb + tid];
  float c[8];
#pragma unroll
  for (int w = 0; w < 8; ++w) c[w] = 0.f;
  const float bi = bih[j] + bhh[j];
  const float bf = bih[CHID + j] + bhh[CHID + j];
  const float bg = bih[2 * CHID + j] + bhh[2 * CHID + j];
  const float bo = bih[3 * CHID + j] + bhh[3 * CHID + j];

  for (int t = 0; t < CLEN; ++t) {
    __syncthreads();
    if (tid < 16) cidx[tid] = chars[(wb + tid) * CLEN + t];
    __syncthreads();
    {
      int e = tid * 4;
      int wi = e >> 6;
      int k = e & 63;
      const float4 v = *(const float4*)(emb + (size_t)cidx[wi] * CDIM + k);
      *(float4*)(&xs[wi][k]) = v;
    }
    __syncthreads();
    float ai[8], af[8], ag[8], ao[8];
#pragma unroll
    for (int w = 0; w < 8; ++w) { ai[w] = bi; af[w] = bf; ag[w] = bg; ao[w] = bo; }
    // x part (K = 64)
    for (int k = 0; k < CDIM; k += 4) {
      float4 w0 = *(const float4*)(Wih + (size_t)j * CDIM + k);
      float4 w1 = *(const float4*)(Wih + (size_t)(CHID + j) * CDIM + k);
      float4 w2 = *(const float4*)(Wih + (size_t)(2 * CHID + j) * CDIM + k);
      float4 w3 = *(const float4*)(Wih + (size_t)(3 * CHID + j) * CDIM + k);
#pragma unroll
      for (int s = 0; s < 4; ++s) {
        float wiv = (&w0.x)[s], wfv = (&w1.x)[s], wgv = (&w2.x)[s], wov = (&w3.x)[s];
#pragma unroll
        for (int w = 0; w < 8; ++w) {
          float xv = xs[grp * 8 + w][k + s];   // wave-uniform -> LDS broadcast
          ai[w] = fmaf(wiv, xv, ai[w]);
          af[w] = fmaf(wfv, xv, af[w]);
          ag[w] = fmaf(wgv, xv, ag[w]);
          ao[w] = fmaf(wov, xv, ao[w]);
        }
      }
    }
    // h part (K = 128)
    for (int k = 0; k < CHID; k += 4) {
      float4 w0 = *(const float4*)(Whh + (size_t)j * CHID + k);
      float4 w1 = *(const float4*)(Whh + (size_t)(CHID + j) * CHID + k);
      float4 w2 = *(const float4*)(Whh + (size_t)(2 * CHID + j) * CHID + k);
      float4 w3 = *(const float4*)(Whh + (size_t)(3 * CHID + j) * CHID + k);
#pragma unroll
      for (int s = 0; s < 4; ++s) {
        float wiv = (&w0.x)[s], wfv = (&w1.x)[s], wgv = (&w2.x)[s], wov = (&w3.x)[s];
#pragma unroll
        for (int w = 0; w < 8; ++w) {
          float hv = hsm[grp * 8 + w][k + s];
          ai[w] = fmaf(wiv, hv, ai[w]);
          af[w] = fmaf(wfv, hv, af[w]);
          ag[w] = fmaf(wgv, hv, ag[w]);
          ao[w] = fmaf(wov, hv, ao[w]);
        }
      }
    }
    __syncthreads();
#pragma unroll
    for (int w = 0; w < 8; ++w) {
      if (t < lens[grp * 8 + w]) {
        float iv = sigmoidf_(ai[w]);
        float fv = sigmoidf_(af[w]);
        float gv = tanhf_(ag[w]);
        float ov = sigmoidf_(ao[w]);
        c[w] = fv * c[w] + iv * gv;
        hsm[grp * 8 + w][j] = ov * tanhf_(c[w]);
      }
    }
  }
#pragma unroll
  for (int w = 0; w < 8; ++w)
    cf[(size_t)(wb + grp * 8 + w) * CHID + j] = c[w];   // feature = final CELL state
}

// ---------------------------------------------------------------------------
// K2: G_x[t][g] = [word_emb[x[t]] | char_feat[t]] @ w_Wih^T + (bih+bhh)
// ---------------------------------------------------------------------------
#define BM 64
#define BN 64
#define BK 32
__global__ __launch_bounds__(256)
void gx_gemm_kernel(const int* __restrict__ x, const float* __restrict__ word_emb,
                    const float* __restrict__ char_feat, const float* __restrict__ Wih,
                    const float* __restrict__ bih, const float* __restrict__ bhh,
                    float* __restrict__ Gx)
{
  __shared__ float As[BK][BM + 1];
  __shared__ float Bs[BK][BN + 1];
  __shared__ int xidx[BM];
  const int tid = threadIdx.x;
  const int tx = tid & 15, ty = tid >> 4;
  const int m0 = blockIdx.y * BM;
  const int n0 = blockIdx.x * BN;
  if (tid < BM) xidx[tid] = x[m0 + tid];
  float acc[4][4] = {};
  for (int k0 = 0; k0 < KDIM; k0 += BK) {
    __syncthreads();
    {
      int i = tid >> 5;
      int kk = tid & 31;
#pragma unroll
      for (int l = 0; l < 8; ++l) {
        int row = i + l * 8;
        int k = k0 + kk;
        int tt = m0 + row;
        float v = (k < WDIM) ? word_emb[(size_t)xidx[row] * WDIM + k]
                             : char_feat[(size_t)tt * CHID + (k - WDIM)];
        As[kk][row] = v;
      }
    }
    {
      int jjj = tid >> 5;
      int kk = tid & 31;
#pragma unroll
      for (int l = 0; l < 8; ++l) {
        int col = jjj + l * 8;
        Bs[kk][col] = Wih[(size_t)(n0 + col) * KDIM + k0 + kk];
      }
    }
    __syncthreads();
#pragma unroll
    for (int kk = 0; kk < BK; ++kk) {
      float a[4], b[4];
#pragma unroll
      for (int m = 0; m < 4; ++m) a[m] = As[kk][ty * 4 + m];
#pragma unroll
      for (int n = 0; n < 4; ++n) b[n] = Bs[kk][tx * 4 + n];
#pragma unroll
      for (int m = 0; m < 4; ++m)
#pragma unroll
        for (int n = 0; n < 4; ++n)
          acc[m][n] = fmaf(a[m], b[n], acc[m][n]);
    }
  }
#pragma unroll
  for (int n = 0; n < 4; ++n) {
    int g = n0 + tx * 4 + n;
    float bias = bih[g] + bhh[g];
#pragma unroll
    for (int m = 0; m < 4; ++m) {
      int tt = m0 + ty * 4 + m;
      Gx[(size_t)tt * GDIM + g] = acc[m][n] + bias;
    }
  }
}

// ---------------------------------------------------------------------------
// K3: sequential word LSTM, v8 = R3 structure + pipelined probes + hybrid
// weights + raw barrier.
//
// 32 WGs x 256 thr, agent-scope tagged slots (R3 proven). Wave cc owns
// k-chunk [128cc,+128); lane = gate row grow. Per step:
//  A. issue (not wait) 16 float4 weight-half loads + Gx load  -> their flight
//     overlaps the poll wait (first vmcnt(1) covers them).
//  B. poll own 2 tagged slots with DEPTH-2 pipelined dwordx4 probes
//     (sc0 sc1), alternately checked via counted s_waitcnt vmcnt(1) +
//     sched_barrier(0). Probe granularity ~halves detect wait. Self-
//     validating: stale-complete data just fails the tag check; dword fill
//     order makes tag1 (last dword) a completion sentinel. After 256 misses
//     latch to the R3-proven intrinsic poll (graceful fallback, no livelock).
//  C. stage own chunk in h_lds; matvec = 16 LDS-private float4 (conflict-
//     free, lanes-consecutive) + 16 register float4 from step A.
//  D. red[par] write; keepalive strays; vmcnt(0) (off-path by now);
//     lgkmcnt(0); RAW s_barrier (no compiler vmcnt drain).
//  E. wave0 finalize + publish (agent atomic exchange, tag t+1), hs store.
// Publish stores stay in flight into the next step (counted at next poll).
// ---------------------------------------------------------------------------
__global__ __launch_bounds__(256, 1)
void word_lstm_seq(const float* __restrict__ Whh, const float* __restrict__ Gx,
                   float* __restrict__ hs, u64* hbuf)
{
  __shared__ __align__(16) float4 wlds4[16 * 256];   // 64 KiB private weight half
  __shared__ float h_lds[WHID];
  __shared__ float red[2][256];
  const int tid  = threadIdx.x;
  const int wg   = blockIdx.x;
  const int cc   = tid >> 6;     // k-chunk 0..3 (one per wave)
  const int lane = tid & 63;
  const int kb   = cc * 128;
  const int grow = (lane >> 4) * WHID + wg * 16 + (lane & 15);

  // one-time: LDS half = k in [kb, kb+64), private layout [j][tid]
  {
    const float* wsrc = Whh + (size_t)grow * WHID + kb;
#pragma unroll
    for (int j = 0; j < 16; ++j)
      wlds4[j * 256 + tid] = *(const float4*)(wsrc + 4 * j);
  }
  const float* __restrict__ wsrc2 = Whh + (size_t)grow * WHID + kb + 64;
  __syncthreads();

  float c_state = 0.f;   // lanes<16 of wave 0
  int use_probes = 1;

  for (int t = 0; t < S_LEN; ++t) {
    const int par = t & 1;
    // ---- A. issue prefetches (no wait): 16 weight float4 + Gx ----
    float4 wr_[16];
#pragma unroll
    for (int i = 0; i < 16; ++i) wr_[i] = *(const float4*)(wsrc2 + 4 * i);
    float gxv = Gx[(size_t)t * GDIM + grow];   // all lanes (uniform vmcnt)
    // ---- B. poll own 2 tagged slots {lo32=value, hi32=tag} ----
    float v0 = 0.f, v1 = 0.f;
    int4 pa = {0, 0, 0, 0}, pb = {0, 0, 0, 0};
    if (t > 0) {
      const unsigned want = (unsigned)t;
      const u64* ps = hbuf + (size_t)par * WHID + kb + 2 * lane;
      bool ok = false;
      int4 rr = {0, 0, 0, 0};
      if (use_probes) {
        asm volatile("global_load_dwordx4 %0, %1, off sc0 sc1"
                     : "=&v"(pa) : "v"(ps) : "memory");
        asm volatile("global_load_dwordx4 %0, %1, off sc0 sc1"
                     : "=&v"(pb) : "v"(ps) : "memory");
        int miss = 0;
        for (;;) {
          asm volatile("s_waitcnt vmcnt(1)" ::: "memory");
          __builtin_amdgcn_sched_barrier(0);
          if ((unsigned)pa.y == want && (unsigned)pa.w == want) {
            rr = pa; ok = true; break;
          }
          asm volatile("global_load_dwordx4 %0, %1, off sc0 sc1"
                       : "=&v"(pa) : "v"(ps) : "memory");
          asm volatile("s_waitcnt vmcnt(1)" ::: "memory");
          __builtin_amdgcn_sched_barrier(0);
          if ((unsigned)pb.y == want && (unsigned)pb.w == want) {
            rr = pb; ok = true; break;
          }
          asm volatile("global_load_dwordx4 %0, %1, off sc0 sc1"
                       : "=&v"(pb) : "v"(ps) : "memory");
          if (++miss >= 256) { use_probes = 0; break; }  // latch to proven path
        }
      }
      if (!ok) {   // R3-proven intrinsic poll (guaranteed live)
        u64 a, b;
        do {
          a = __hip_atomic_load(ps + 0, __ATOMIC_RELAXED, __HIP_MEMORY_SCOPE_AGENT);
          b = __hip_atomic_load(ps + 1, __ATOMIC_RELAXED, __HIP_MEMORY_SCOPE_AGENT);
        } while (((unsigned)(a >> 32) != want) | ((unsigned)(b >> 32) != want));
        v0 = __uint_as_float((unsigned)a);
        v1 = __uint_as_float((unsigned)b);
      } else {
        v0 = __int_as_float(rr.x);
        v1 = __int_as_float(rr.z);
      }
    }
    // ---- C. stage own chunk; matvec (LDS half + register half) ----
    *(float2*)(&h_lds[kb + 2 * lane]) = make_float2(v0, v1);
    __threadfence_block();
    float acc = 0.f;
#pragma unroll
    for (int j = 0; j < 16; ++j) {
      const float4 wv = wlds4[j * 256 + tid];
      const float4 hv = *(const float4*)(&h_lds[kb + 4 * j]);
      acc = fmaf(wv.x, hv.x, acc);
      acc = fmaf(wv.y, hv.y, acc);
      acc = fmaf(wv.z, hv.z, acc);
      acc = fmaf(wv.w, hv.w, acc);
    }
#pragma unroll
    for (int i = 0; i < 16; ++i) {
      const float4 hv = *(const float4*)(&h_lds[kb + 64 + 4 * i]);
      acc = fmaf(wr_[i].x, hv.x, acc);
      acc = fmaf(wr_[i].y, hv.y, acc);
      acc = fmaf(wr_[i].z, hv.z, acc);
      acc = fmaf(wr_[i].w, hv.w, acc);
    }
    red[par][tid] = acc;
    // ---- D. stray-probe hygiene + raw barrier ----
    asm volatile("" :: "v"(pa.x), "v"(pa.y), "v"(pa.z), "v"(pa.w),
                       "v"(pb.x), "v"(pb.y), "v"(pb.z), "v"(pb.w));
    asm volatile("s_waitcnt vmcnt(0)" ::: "memory");   // strays done by now
    asm volatile("s_waitcnt lgkmcnt(0)" ::: "memory"); // red visible
    __builtin_amdgcn_s_barrier();
    // ---- E. wave0 finalize + publish ----
    if (tid < 64) {
      const float* rp = red[par];
      float s = rp[tid] + rp[64 + tid] + rp[128 + tid] + rp[192 + tid] + gxv;
      float act = ((tid >> 4) == 2) ? tanhf_(s) : sigmoidf_(s);
      int jj = tid & 15;
      float iv = __shfl(act, jj);
      float fv = __shfl(act, 16 + jj);
      float gv = __shfl(act, 32 + jj);
      float ov = __shfl(act, 48 + jj);
      if (tid < 16) {
        c_state = fv * c_state + iv * gv;
        float hv = ov * tanhf_(c_state);
        const int hidx = wg * 16 + tid;
        const u64 pkt = ((u64)(unsigned)(t + 1) << 32) | (u64)__float_as_uint(hv);
        (void)__hip_atomic_exchange(&hbuf[(size_t)((t + 1) & 1) * WHID + hidx],
                                    pkt, __ATOMIC_RELAXED,
                                    __HIP_MEMORY_SCOPE_AGENT);
        hs[(size_t)t * WHID + hidx] = hv;
      }
    }
  }
}

// ---------------------------------------------------------------------------
// K4: logits + log_softmax. One 64-lane wave per row t; lane = tag.
// ---------------------------------------------------------------------------
__global__ __launch_bounds__(256)
void tag_kernel(const float* __restrict__ hs, const float* __restrict__ W,
                const float* __restrict__ b, float* __restrict__ out)
{
  const int wave = threadIdx.x >> 6;
  const int lane = threadIdx.x & 63;
  const int t = blockIdx.x * 4 + wave;
  const float* hr = hs + (size_t)t * WHID;
  const float* wr = W + (size_t)lane * WHID;
  float acc = b[lane];
  for (int k = 0; k < WHID; k += 4) {
    float4 wv = *(const float4*)(wr + k);
    float4 hv = *(const float4*)(hr + k);
    acc = fmaf(wv.x, hv.x, acc);
    acc = fmaf(wv.y, hv.y, acc);
    acc = fmaf(wv.z, hv.z, acc);
    acc = fmaf(wv.w, hv.w, acc);
  }
  float m = acc;
#pragma unroll
  for (int off = 32; off > 0; off >>= 1) m = fmaxf(m, __shfl_xor(m, off));
  float e = __expf(acc - m);
  float sum = e;
#pragma unroll
  for (int off = 32; off > 0; off >>= 1) sum += __shfl_xor(sum, off);
  out[(size_t)t * NTAG + lane] = (acc - m) - __logf(sum);
}

extern "C" void kernel_launch(void* const* d_in, const int* in_sizes, int n_in,
                              void* d_out, int out_size, void* d_ws, size_t ws_size,
                              hipStream_t stream)
{
  const int* x          = (const int*)d_in[0];
  const int* chars      = (const int*)d_in[1];
  const int* lengths    = (const int*)d_in[2];
  const float* word_emb = (const float*)d_in[3];
  const float* char_emb = (const float*)d_in[4];
  const float* c_Wih    = (const float*)d_in[5];
  const float* c_Whh    = (const float*)d_in[6];
  const float* c_bih    = (const float*)d_in[7];
  const float* c_bhh    = (const float*)d_in[8];
  const float* w_Wih    = (const float*)d_in[9];
  const float* w_Whh    = (const float*)d_in[10];
  const float* w_bih    = (const float*)d_in[11];
  const float* w_bhh    = (const float*)d_in[12];
  const float* lin_W    = (const float*)d_in[13];
  const float* lin_b    = (const float*)d_in[14];
  float* out = (float*)d_out;

  char* ws = (char*)d_ws;
  // layout: [0,8192) hbuf (2 x 512 u64 tagged slots) |
  //         char_feat 4 MiB | Gx 64 MiB | hs 16 MiB   (total ~84 MiB)
  u64*   hbuf      = (u64*)ws;
  float* char_feat = (float*)(ws + 8192);
  float* Gx        = (float*)(ws + 8192 + (size_t)S_LEN * CHID * 4);
  float* hs        = (float*)(ws + 8192 + (size_t)S_LEN * CHID * 4
                                        + (size_t)S_LEN * GDIM * 4);

  // zero tags every call (tag 0 never matches an expected epoch t >= 1)
  hipMemsetAsync(ws, 0, 8192, stream);

  char_lstm_kernel<<<S_LEN / 16, 256, 0, stream>>>(
      chars, lengths, char_emb, c_Wih, c_Whh, c_bih, c_bhh, char_feat);

  dim3 g2(GDIM / BN, S_LEN / BM);
  gx_gemm_kernel<<<g2, 256, 0, stream>>>(
      x, word_emb, char_feat, w_Wih, w_bih, w_bhh, Gx);

  word_lstm_seq<<<NWG, 256, 0, stream>>>(w_Whh, Gx, hs, hbuf);

  tag_kernel<<<S_LEN / 4, 256, 0, stream>>>(hs, lin_W, lin_b, out);
}

// Round 9
// 17097.884 us; speedup vs baseline: 1.0660x; 1.0660x over previous
//
#include <hip/hip_runtime.h>
#include <hip/hip_bf16.h>

#define S_LEN 8192
#define CLEN 16
#define WDIM 256
#define CDIM 64
#define CHID 128
#define WHID 512
#define GDIM 2048   // 4*WHID
#define NTAG 64
#define KDIM 384    // WDIM + CHID
#define NWG 32      // workgroups in sequential kernel

typedef unsigned long long u64;

__device__ __forceinline__ float sigmoidf_(float x) {
  return 1.0f / (1.0f + __expf(-x));
}
__device__ __forceinline__ float tanhf_(float x) {
  // safe tanh: 1 - 2/(e^{2x}+1); correct limits at +-inf without NaN
  return 1.0f - 2.0f / (__expf(2.0f * x) + 1.0f);
}

// ---------------------------------------------------------------------------
// K1: batched char LSTM. 16 words per block (two groups of 8), 256 threads.
// ---------------------------------------------------------------------------
__global__ __launch_bounds__(256)
void char_lstm_kernel(const int* __restrict__ chars, const int* __restrict__ lengths,
                      const float* __restrict__ emb, const float* __restrict__ Wih,
                      const float* __restrict__ Whh, const float* __restrict__ bih,
                      const float* __restrict__ bhh, float* __restrict__ cf)
{
  __shared__ float xs[16][CDIM];
  __shared__ float hsm[16][CHID];
  __shared__ int cidx[16];
  __shared__ int lens[16];
  const int tid = threadIdx.x;
  const int grp = tid >> 7;      // 0..1 (word group)
  const int j = tid & 127;       // hidden index
  const int wb = blockIdx.x * 16;

  for (int i = tid; i < 16 * CHID; i += 256) (&hsm[0][0])[i] = 0.f;
  if (tid < 16) lens[tid] = lengths[wb + tid];
  float c[8];
#pragma unroll
  for (int w = 0; w < 8; ++w) c[w] = 0.f;
  const float bi = bih[j] + bhh[j];
  const float bf = bih[CHID + j] + bhh[CHID + j];
  const float bg = bih[2 * CHID + j] + bhh[2 * CHID + j];
  const float bo = bih[3 * CHID + j] + bhh[3 * CHID + j];

  for (int t = 0; t < CLEN; ++t) {
    __syncthreads();
    if (tid < 16) cidx[tid] = chars[(wb + tid) * CLEN + t];
    __syncthreads();
    {
      int e = tid * 4;
      int wi = e >> 6;
      int k = e & 63;
      const float4 v = *(const float4*)(emb + (size_t)cidx[wi] * CDIM + k);
      *(float4*)(&xs[wi][k]) = v;
    }
    __syncthreads();
    float ai[8], af[8], ag[8], ao[8];
#pragma unroll
    for (int w = 0; w < 8; ++w) { ai[w] = bi; af[w] = bf; ag[w] = bg; ao[w] = bo; }
    // x part (K = 64)
    for (int k = 0; k < CDIM; k += 4) {
      float4 w0 = *(const float4*)(Wih + (size_t)j * CDIM + k);
      float4 w1 = *(const float4*)(Wih + (size_t)(CHID + j) * CDIM + k);
      float4 w2 = *(const float4*)(Wih + (size_t)(2 * CHID + j) * CDIM + k);
      float4 w3 = *(const float4*)(Wih + (size_t)(3 * CHID + j) * CDIM + k);
#pragma unroll
      for (int s = 0; s < 4; ++s) {
        float wiv = (&w0.x)[s], wfv = (&w1.x)[s], wgv = (&w2.x)[s], wov = (&w3.x)[s];
#pragma unroll
        for (int w = 0; w < 8; ++w) {
          float xv = xs[grp * 8 + w][k + s];   // wave-uniform -> LDS broadcast
          ai[w] = fmaf(wiv, xv, ai[w]);
          af[w] = fmaf(wfv, xv, af[w]);
          ag[w] = fmaf(wgv, xv, ag[w]);
          ao[w] = fmaf(wov, xv, ao[w]);
        }
      }
    }
    // h part (K = 128)
    for (int k = 0; k < CHID; k += 4) {
      float4 w0 = *(const float4*)(Whh + (size_t)j * CHID + k);
      float4 w1 = *(const float4*)(Whh + (size_t)(CHID + j) * CHID + k);
      float4 w2 = *(const float4*)(Whh + (size_t)(2 * CHID + j) * CHID + k);
      float4 w3 = *(const float4*)(Whh + (size_t)(3 * CHID + j) * CHID + k);
#pragma unroll
      for (int s = 0; s < 4; ++s) {
        float wiv = (&w0.x)[s], wfv = (&w1.x)[s], wgv = (&w2.x)[s], wov = (&w3.x)[s];
#pragma unroll
        for (int w = 0; w < 8; ++w) {
          float hv = hsm[grp * 8 + w][k + s];
          ai[w] = fmaf(wiv, hv, ai[w]);
          af[w] = fmaf(wfv, hv, af[w]);
          ag[w] = fmaf(wgv, hv, ag[w]);
          ao[w] = fmaf(wov, hv, ao[w]);
        }
      }
    }
    __syncthreads();
#pragma unroll
    for (int w = 0; w < 8; ++w) {
      if (t < lens[grp * 8 + w]) {
        float iv = sigmoidf_(ai[w]);
        float fv = sigmoidf_(af[w]);
        float gv = tanhf_(ag[w]);
        float ov = sigmoidf_(ao[w]);
        c[w] = fv * c[w] + iv * gv;
        hsm[grp * 8 + w][j] = ov * tanhf_(c[w]);
      }
    }
  }
#pragma unroll
  for (int w = 0; w < 8; ++w)
    cf[(size_t)(wb + grp * 8 + w) * CHID + j] = c[w];   // feature = final CELL state
}

// ---------------------------------------------------------------------------
// K2: G_x[t][g] = [word_emb[x[t]] | char_feat[t]] @ w_Wih^T + (bih+bhh)
// ---------------------------------------------------------------------------
#define BM 64
#define BN 64
#define BK 32
__global__ __launch_bounds__(256)
void gx_gemm_kernel(const int* __restrict__ x, const float* __restrict__ word_emb,
                    const float* __restrict__ char_feat, const float* __restrict__ Wih,
                    const float* __restrict__ bih, const float* __restrict__ bhh,
                    float* __restrict__ Gx)
{
  __shared__ float As[BK][BM + 1];
  __shared__ float Bs[BK][BN + 1];
  __shared__ int xidx[BM];
  const int tid = threadIdx.x;
  const int tx = tid & 15, ty = tid >> 4;
  const int m0 = blockIdx.y * BM;
  const int n0 = blockIdx.x * BN;
  if (tid < BM) xidx[tid] = x[m0 + tid];
  float acc[4][4] = {};
  for (int k0 = 0; k0 < KDIM; k0 += BK) {
    __syncthreads();
    {
      int i = tid >> 5;
      int kk = tid & 31;
#pragma unroll
      for (int l = 0; l < 8; ++l) {
        int row = i + l * 8;
        int k = k0 + kk;
        int tt = m0 + row;
        float v = (k < WDIM) ? word_emb[(size_t)xidx[row] * WDIM + k]
                             : char_feat[(size_t)tt * CHID + (k - WDIM)];
        As[kk][row] = v;
      }
    }
    {
      int jjj = tid >> 5;
      int kk = tid & 31;
#pragma unroll
      for (int l = 0; l < 8; ++l) {
        int col = jjj + l * 8;
        Bs[kk][col] = Wih[(size_t)(n0 + col) * KDIM + k0 + kk];
      }
    }
    __syncthreads();
#pragma unroll
    for (int kk = 0; kk < BK; ++kk) {
      float a[4], b[4];
#pragma unroll
      for (int m = 0; m < 4; ++m) a[m] = As[kk][ty * 4 + m];
#pragma unroll
      for (int n = 0; n < 4; ++n) b[n] = Bs[kk][tx * 4 + n];
#pragma unroll
      for (int m = 0; m < 4; ++m)
#pragma unroll
        for (int n = 0; n < 4; ++n)
          acc[m][n] = fmaf(a[m], b[n], acc[m][n]);
    }
  }
#pragma unroll
  for (int n = 0; n < 4; ++n) {
    int g = n0 + tx * 4 + n;
    float bias = bih[g] + bhh[g];
#pragma unroll
    for (int m = 0; m < 4; ++m) {
      int tt = m0 + ty * 4 + m;
      Gx[(size_t)tt * GDIM + g] = acc[m][n] + bias;
    }
  }
}

// ---------------------------------------------------------------------------
// K3: sequential word LSTM, v9 = EXACT round-3 structure (13.88 ms proven:
// intrinsic-only tagged-slot sync, one barrier, wave0 finalize, atomic-u64
// loads so no tearing) with ONE change: the WG's full 128 KB weight slice is
// LDS-resident in a float4-transposed conflict-free layout
//   wlds4[cc][j][r] = Whh[row(r)][cc*128 + 4j .. +4)
// so the matvec reads lane-consecutive ds_read_b128 (no L2 latency on the
// critical path -- R3's VGPR=84 meant the compiler refetched all 32 weight
// float4s from L2 inside the matvec, serialized after the poll).
// A/B vs R3 isolates the "matvec is L2-latency-bound" hypothesis.
// ---------------------------------------------------------------------------
__global__ __launch_bounds__(256, 1)
void word_lstm_seq(const float* __restrict__ Whh, const float* __restrict__ Gx,
                   float* __restrict__ hs, u64* hbuf)
{
  extern __shared__ float4 wlds4[];   // [4][32][64] float4 = 128 KiB
  __shared__ float h_lds[WHID];
  __shared__ float red[2][256];
  const int tid  = threadIdx.x;
  const int wg   = blockIdx.x;
  const int cc   = tid >> 6;     // k-chunk 0..3 (one per wave)
  const int lane = tid & 63;     // gate row within WG slice
  const int kb   = cc * 128;
  const int grow = (lane >> 4) * WHID + wg * 16 + (lane & 15);

  // one-time staging: wlds4[c2*2048 + j*64 + r] = Whh[row(r)][c2*128+4j ..+4)
  for (int L = tid; L < 8192; L += 256) {
    int c2  = L >> 11;           // 0..3
    int rem = L & 2047;
    int j   = rem >> 6;          // 0..31
    int r   = rem & 63;
    int gr  = (r >> 4) * WHID + wg * 16 + (r & 15);
    wlds4[L] = *(const float4*)(Whh + (size_t)gr * WHID + c2 * 128 + 4 * j);
  }
  __syncthreads();

  float c_state = 0.f;   // lanes<16 of wave 0 use

  for (int t = 0; t < S_LEN; ++t) {
    const int par = t & 1;
    float gxv = 0.f;
    if (tid < 64)
      gxv = Gx[(size_t)t * GDIM + grow];   // issued before poll; latency hides
    // ---- poll own 2 tagged slots (atomic u64: tag+value arrive together) ----
    float v0 = 0.f, v1 = 0.f;
    if (t > 0) {
      const u64* ps = hbuf + (size_t)par * WHID + kb + 2 * lane;
      const unsigned want = (unsigned)t;
      u64 a, b;
      do {
        a = __hip_atomic_load(ps + 0, __ATOMIC_RELAXED, __HIP_MEMORY_SCOPE_AGENT);
        b = __hip_atomic_load(ps + 1, __ATOMIC_RELAXED, __HIP_MEMORY_SCOPE_AGENT);
      } while (((unsigned)(a >> 32) != want) | ((unsigned)(b >> 32) != want));
      v0 = __uint_as_float((unsigned)a);
      v1 = __uint_as_float((unsigned)b);
    }
    // ---- stage own chunk (wave-private LDS region) ----
    *(float2*)(&h_lds[kb + 2 * lane]) = make_float2(v0, v1);
    __threadfence_block();
    // ---- matvec: LDS-resident weights (lane-consecutive b128, conflict-
    //      free), h broadcast from LDS ----
    const float4* wp = wlds4 + cc * 2048;
    float acc = 0.f;
#pragma unroll
    for (int j = 0; j < 32; ++j) {
      const float4 wv = wp[j * 64 + lane];
      const float4 hv = *(const float4*)(&h_lds[kb + 4 * j]);
      acc = fmaf(wv.x, hv.x, acc);
      acc = fmaf(wv.y, hv.y, acc);
      acc = fmaf(wv.z, hv.z, acc);
      acc = fmaf(wv.w, hv.w, acc);
    }
    red[par][tid] = acc;
    __syncthreads();   // the ONLY barrier per step
    // ---- wave0 finalize + publish (R3 verbatim) ----
    if (tid < 64) {
      const float* rp = red[par];
      float s = rp[tid] + rp[64 + tid] + rp[128 + tid] + rp[192 + tid] + gxv;
      float act = ((tid >> 4) == 2) ? tanhf_(s) : sigmoidf_(s);
      int jj = tid & 15;
      float iv = __shfl(act, jj);
      float fv = __shfl(act, 16 + jj);
      float gv = __shfl(act, 32 + jj);
      float ov = __shfl(act, 48 + jj);
      if (tid < 16) {
        c_state = fv * c_state + iv * gv;
        float hv = ov * tanhf_(c_state);
        const int hidx = wg * 16 + tid;
        const u64 pkt = ((u64)(unsigned)(t + 1) << 32) | (u64)__float_as_uint(hv);
        (void)__hip_atomic_exchange(&hbuf[(size_t)((t + 1) & 1) * WHID + hidx],
                                    pkt, __ATOMIC_RELAXED,
                                    __HIP_MEMORY_SCOPE_AGENT);
        hs[(size_t)t * WHID + hidx] = hv;
      }
    }
  }
}

// ---------------------------------------------------------------------------
// K4: logits + log_softmax. One 64-lane wave per row t; lane = tag.
// ---------------------------------------------------------------------------
__global__ __launch_bounds__(256)
void tag_kernel(const float* __restrict__ hs, const float* __restrict__ W,
                const float* __restrict__ b, float* __restrict__ out)
{
  const int wave = threadIdx.x >> 6;
  const int lane = threadIdx.x & 63;
  const int t = blockIdx.x * 4 + wave;
  const float* hr = hs + (size_t)t * WHID;
  const float* wr = W + (size_t)lane * WHID;
  float acc = b[lane];
  for (int k = 0; k < WHID; k += 4) {
    float4 wv = *(const float4*)(wr + k);
    float4 hv = *(const float4*)(hr + k);
    acc = fmaf(wv.x, hv.x, acc);
    acc = fmaf(wv.y, hv.y, acc);
    acc = fmaf(wv.z, hv.z, acc);
    acc = fmaf(wv.w, hv.w, acc);
  }
  float m = acc;
#pragma unroll
  for (int off = 32; off > 0; off >>= 1) m = fmaxf(m, __shfl_xor(m, off));
  float e = __expf(acc - m);
  float sum = e;
#pragma unroll
  for (int off = 32; off > 0; off >>= 1) sum += __shfl_xor(sum, off);
  out[(size_t)t * NTAG + lane] = (acc - m) - __logf(sum);
}

extern "C" void kernel_launch(void* const* d_in, const int* in_sizes, int n_in,
                              void* d_out, int out_size, void* d_ws, size_t ws_size,
                              hipStream_t stream)
{
  const int* x          = (const int*)d_in[0];
  const int* chars      = (const int*)d_in[1];
  const int* lengths    = (const int*)d_in[2];
  const float* word_emb = (const float*)d_in[3];
  const float* char_emb = (const float*)d_in[4];
  const float* c_Wih    = (const float*)d_in[5];
  const float* c_Whh    = (const float*)d_in[6];
  const float* c_bih    = (const float*)d_in[7];
  const float* c_bhh    = (const float*)d_in[8];
  const float* w_Wih    = (const float*)d_in[9];
  const float* w_Whh    = (const float*)d_in[10];
  const float* w_bih    = (const float*)d_in[11];
  const float* w_bhh    = (const float*)d_in[12];
  const float* lin_W    = (const float*)d_in[13];
  const float* lin_b    = (const float*)d_in[14];
  float* out = (float*)d_out;

  char* ws = (char*)d_ws;
  // layout: [0,8192) hbuf (2 x 512 u64 tagged slots) |
  //         char_feat 4 MiB | Gx 64 MiB | hs 16 MiB   (total ~84 MiB)
  u64*   hbuf      = (u64*)ws;
  float* char_feat = (float*)(ws + 8192);
  float* Gx        = (float*)(ws + 8192 + (size_t)S_LEN * CHID * 4);
  float* hs        = (float*)(ws + 8192 + (size_t)S_LEN * CHID * 4
                                        + (size_t)S_LEN * GDIM * 4);

  // zero tags every call (tag 0 never matches an expected epoch t >= 1)
  hipMemsetAsync(ws, 0, 8192, stream);

  char_lstm_kernel<<<S_LEN / 16, 256, 0, stream>>>(
      chars, lengths, char_emb, c_Wih, c_Whh, c_bih, c_bhh, char_feat);

  dim3 g2(GDIM / BN, S_LEN / BM);
  gx_gemm_kernel<<<g2, 256, 0, stream>>>(
      x, word_emb, char_feat, w_Wih, w_bih, w_bhh, Gx);

  hipFuncSetAttribute((const void*)word_lstm_seq,
                      hipFuncAttributeMaxDynamicSharedMemorySize, 131072);
  word_lstm_seq<<<NWG, 256, 131072, stream>>>(w_Whh, Gx, hs, hbuf);

  tag_kernel<<<S_LEN / 4, 256, 0, stream>>>(hs, lin_W, lin_b, out);
}